// Round 1
// baseline (792.655 us; speedup 1.0000x reference)
//
#include <hip/hip_runtime.h>

#define BB 8
#define CIN 64
#define COUT 64
#define HH 256
#define WW 256

constexpr int TILE = 32;   // 32x32 spatial tile per block
constexpr int CO_T = 16;   // output channels per block
constexpr int CI_T = 8;    // input-channel chunk staged in LDS
constexpr int XH = 34;     // tile + halo rows
constexpr int XROW = 40;   // padded row stride (40 % 32 = 8 -> 2-way max conflict)

__global__ __launch_bounds__(256, 2) void maskconv_kernel(
    const float* __restrict__ x, const int* __restrict__ mask,
    const float* __restrict__ wgt, const float* __restrict__ bias,
    float* __restrict__ out)
{
    __shared__ float xs[CI_T][XH][XROW];
    __shared__ float ws[CI_T][3][3][CO_T];

    const int tid = threadIdx.x;
    const int tx = tid & 15;
    const int ty = tid >> 4;

    const int bx = blockIdx.x;            // 64 spatial tiles (8x8)
    const int tw = (bx & 7) * TILE;
    const int th = (bx >> 3) * TILE;
    const int co0 = blockIdx.y * CO_T;
    const int b  = blockIdx.z;

    float acc[CO_T][2][2];
    #pragma unroll
    for (int c = 0; c < CO_T; ++c)
        #pragma unroll
        for (int dy = 0; dy < 2; ++dy)
            #pragma unroll
            for (int dx = 0; dx < 2; ++dx)
                acc[c][dy][dx] = 0.f;

    const float* xb = x + (size_t)b * CIN * HH * WW;

    for (int ci0 = 0; ci0 < CIN; ci0 += CI_T) {
        // ---- stage x tile (with zero halo) ----
        for (int t = tid; t < CI_T * XH * 34; t += 256) {
            int ci = t / (XH * 34);
            int rem = t - ci * (XH * 34);
            int r = rem / 34;
            int c = rem - r * 34;
            int gr = th - 1 + r;
            int gc = tw - 1 + c;
            float v = 0.f;
            if ((unsigned)gr < HH && (unsigned)gc < WW)
                v = xb[((size_t)(ci0 + ci) * HH + gr) * WW + gc];
            xs[ci][r][c] = v;
        }
        // ---- stage weights [ci][kh][kw][co] ----
        for (int t = tid; t < CI_T * 9 * CO_T; t += 256) {
            int co = t & (CO_T - 1);
            int u = t >> 4;          // 0..71
            int ci = u / 9;
            int k = u - ci * 9;
            ws[ci][k / 3][k % 3][co] =
                wgt[((size_t)(co0 + co) * CIN + (ci0 + ci)) * 9 + k];
        }
        __syncthreads();

        for (int ci = 0; ci < CI_T; ++ci) {
            #pragma unroll
            for (int kh = 0; kh < 3; ++kh) {
                #pragma unroll
                for (int kw = 0; kw < 3; ++kw) {
                    float xv00 = xs[ci][ty + kh][tx + kw];
                    float xv01 = xs[ci][ty + kh][tx + 16 + kw];
                    float xv10 = xs[ci][ty + 16 + kh][tx + kw];
                    float xv11 = xs[ci][ty + 16 + kh][tx + 16 + kw];
                    #pragma unroll
                    for (int co = 0; co < CO_T; ++co) {
                        float wv = ws[ci][kh][kw][co];
                        acc[co][0][0] = fmaf(wv, xv00, acc[co][0][0]);
                        acc[co][0][1] = fmaf(wv, xv01, acc[co][0][1]);
                        acc[co][1][0] = fmaf(wv, xv10, acc[co][1][0]);
                        acc[co][1][1] = fmaf(wv, xv11, acc[co][1][1]);
                    }
                }
            }
        }
        __syncthreads();
    }

    // ---- epilogue: bias + mask, write all outputs (mask=0 -> exact 0) ----
    const int* mb = mask + b * HH * WW;
    float m[2][2];
    #pragma unroll
    for (int dy = 0; dy < 2; ++dy)
        #pragma unroll
        for (int dx = 0; dx < 2; ++dx)
            m[dy][dx] = (float)mb[(th + ty + dy * 16) * WW + (tw + tx + dx * 16)];

    #pragma unroll
    for (int co = 0; co < CO_T; ++co) {
        float bv = bias[co0 + co];
        float* ob = out + ((size_t)b * COUT + co0 + co) * HH * WW;
        #pragma unroll
        for (int dy = 0; dy < 2; ++dy)
            #pragma unroll
            for (int dx = 0; dx < 2; ++dx)
                ob[(th + ty + dy * 16) * WW + (tw + tx + dx * 16)] =
                    (acc[co][dy][dx] + bv) * m[dy][dx];
    }
}

extern "C" void kernel_launch(void* const* d_in, const int* in_sizes, int n_in,
                              void* d_out, int out_size, void* d_ws, size_t ws_size,
                              hipStream_t stream) {
    const float* x    = (const float*)d_in[0];
    const int*   mask = (const int*)d_in[1];
    const float* wgt  = (const float*)d_in[2];
    const float* bias = (const float*)d_in[3];
    float* out = (float*)d_out;

    dim3 grid(64, COUT / CO_T, BB);   // 64 spatial tiles, 4 co-blocks, 8 batches
    dim3 block(256);
    maskconv_kernel<<<grid, block, 0, stream>>>(x, mask, wgt, bias, out);
}

// Round 2
// 138.442 us; speedup vs baseline: 5.7255x; 5.7255x over previous
//
#include <hip/hip_runtime.h>

typedef __attribute__((ext_vector_type(8))) short bf16x8;
typedef __attribute__((ext_vector_type(4))) float f32x4;

#define HWSZ 65536

__device__ inline unsigned short to_bf16(float f) {
    union { float f; unsigned u; } c; c.f = f;
    unsigned u = c.u;
    unsigned r = (u + 0x7fffu + ((u >> 16) & 1u)) >> 16;   // round-nearest-even
    return (unsigned short)r;
}

__global__ __launch_bounds__(512, 2) void maskconv_mfma(
    const float* __restrict__ x, const int* __restrict__ mask,
    const float* __restrict__ wgt, const float* __restrict__ bias,
    float* __restrict__ out)
{
    __shared__ unsigned short xs[34 * 34 * 32];   // 73984 B, [pixel][ci32] bf16, swizzled
    __shared__ unsigned short wl[9 * 64 * 32];    // 36864 B, [kpos][co][ci32] bf16, swizzled

    const int tid  = threadIdx.x;
    const int lane = tid & 63;
    const int wv   = tid >> 6;         // wave 0..7
    const int l15  = lane & 15;
    const int l4   = lane >> 4;        // 0..3

    const int tileid = blockIdx.x;     // 0..63
    const int tw = (tileid & 7) * 32;
    const int th = (tileid >> 3) * 32;
    const int b  = blockIdx.y;

    const float* xb = x + (size_t)b * 64 * HWSZ;

    f32x4 acc[8][4];
    #pragma unroll
    for (int f = 0; f < 8; ++f)
        #pragma unroll
        for (int j = 0; j < 4; ++j)
            acc[f][j] = (f32x4){0.f, 0.f, 0.f, 0.f};

    char* xsb = (char*)xs;
    char* wlb = (char*)wl;
    const int hl = wv * 4;             // wave's first local output row

    for (int chunk = 0; chunk < 2; ++chunk) {
        const int ci0 = chunk * 32;

        // ---- stage weights: wl[kpos][co][ci32], ci-octet G stored at slot G^((co>>1)&3)
        for (int idx = tid; idx < 18432; idx += 512) {
            int kpos = idx % 9;
            int t2   = idx / 9;
            int ci   = t2 & 31;
            int co   = t2 >> 5;
            float v = wgt[((size_t)co * 64 + ci0 + ci) * 9 + kpos];
            int slot = (ci >> 3) ^ ((co >> 1) & 3);
            *(unsigned short*)(wlb + (kpos * 64 + co) * 64 + (slot << 4) + (ci & 7) * 2)
                = to_bf16(v);
        }

        // ---- stage x tile: xs[pi][ci32], ci-octet G stored at slot G^((lc>>1)&3)
        {
            const int q  = tid >> 6;      // ci quad 0..7 (ci = 4q..4q+3)
            const int pl = tid & 63;
            const float* srcbase = xb + (size_t)(ci0 + q * 4) * HWSZ;
            #pragma unroll 1
            for (int pass = 0; pass < 19; ++pass) {
                int pi = pass * 64 + pl;
                if (pi < 1156) {
                    int r  = pi / 34;
                    int lc = pi - r * 34;
                    int gr = th - 1 + r;
                    int gc = tw - 1 + lc;
                    bool inb = ((unsigned)gr < 256u) & ((unsigned)gc < 256u);
                    const float* src = srcbase + gr * 256 + gc;
                    float v0 = inb ? src[0]        : 0.f;
                    float v1 = inb ? src[HWSZ]     : 0.f;
                    float v2 = inb ? src[2 * HWSZ] : 0.f;
                    float v3 = inb ? src[3 * HWSZ] : 0.f;
                    ushort4 hv;
                    hv.x = to_bf16(v0); hv.y = to_bf16(v1);
                    hv.z = to_bf16(v2); hv.w = to_bf16(v3);
                    int s = (lc >> 1) & 3;
                    int off = pi * 64 + (((q >> 1) ^ s) << 4) + (q & 1) * 8;
                    *(ushort4*)(xsb + off) = hv;
                }
            }
        }
        __syncthreads();

        // ---- MFMA: 9 kpos-steps, K=32 ci per step
        #pragma unroll
        for (int kh = 0; kh < 3; ++kh) {
            #pragma unroll
            for (int kw = 0; kw < 3; ++kw) {
                const int kpos = kh * 3 + kw;
                bf16x8 bfrag[4];
                #pragma unroll
                for (int j = 0; j < 4; ++j) {
                    int co = j * 16 + l15;
                    int slot = l4 ^ ((co >> 1) & 3);
                    bfrag[j] = *(const bf16x8*)(wlb + (kpos * 64 + co) * 64 + (slot << 4));
                }
                #pragma unroll
                for (int f = 0; f < 8; ++f) {
                    int lc = (f & 1) * 16 + l15 + kw;
                    int r  = hl + (f >> 1) + kh;
                    int s  = (lc >> 1) & 3;
                    bf16x8 afrag = *(const bf16x8*)(xsb + (r * 34 + lc) * 64 + ((l4 ^ s) << 4));
                    #pragma unroll
                    for (int j = 0; j < 4; ++j)
                        acc[f][j] = __builtin_amdgcn_mfma_f32_16x16x32_bf16(
                            afrag, bfrag[j], acc[f][j], 0, 0, 0);
                }
            }
        }
        __syncthreads();
    }

    // ---- epilogue: bias (fp32) + mask, float4 stores
    const int* mb = mask + (size_t)b * HWSZ;
    float bv[4];
    #pragma unroll
    for (int j = 0; j < 4; ++j) bv[j] = bias[j * 16 + l15];

    #pragma unroll
    for (int f = 0; f < 8; ++f) {
        int h  = th + hl + (f >> 1);
        int wq = tw + (f & 1) * 16 + l4 * 4;
        int4 mv = *(const int4*)(mb + h * 256 + wq);
        float m0 = (float)mv.x, m1 = (float)mv.y, m2 = (float)mv.z, m3 = (float)mv.w;
        #pragma unroll
        for (int j = 0; j < 4; ++j) {
            int co = j * 16 + l15;
            float4 o;
            o.x = (acc[f][j].x + bv[j]) * m0;
            o.y = (acc[f][j].y + bv[j]) * m1;
            o.z = (acc[f][j].z + bv[j]) * m2;
            o.w = (acc[f][j].w + bv[j]) * m3;
            *(float4*)(out + (((size_t)(b * 64 + co)) << 16) + h * 256 + wq) = o;
        }
    }
}

extern "C" void kernel_launch(void* const* d_in, const int* in_sizes, int n_in,
                              void* d_out, int out_size, void* d_ws, size_t ws_size,
                              hipStream_t stream) {
    const float* x    = (const float*)d_in[0];
    const int*   mask = (const int*)d_in[1];
    const float* wgt  = (const float*)d_in[2];
    const float* bias = (const float*)d_in[3];
    float* out = (float*)d_out;

    dim3 grid(64, 8, 1);
    dim3 block(512, 1, 1);
    maskconv_mfma<<<grid, block, 0, stream>>>(x, mask, wgt, bias, out);
}